// Round 3
// baseline (77.675 us; speedup 1.0000x reference)
//
#include <hip/hip_runtime.h>
#include <hip/hip_bf16.h>

#define T_LEN 2048
#define NCOMP 8
#define HID 64
#define OUT_DIM 64
#define BATCH 64
#define MAX_EVENTS (T_LEN * NCOMP)
#define NCHUNK 32              // 2048 / 64 bit-chunks per channel
#define PART_STRIDE 66         // 64 sums + count + pad

typedef unsigned long long u64;

// ws layout:
//   [0, 131072)       : u64 words[64][8][32]
//   [131072, +135168) : float partial[64][8][66]
//   [266240, +256)    : int tickets[64]
#define WORDS_BYTES   (64ULL * NCOMP * NCHUNK * 8)
#define PARTIAL_BYTES (64ULL * NCOMP * PART_STRIDE * 4)

// ---------------------------------------------------------------------------
// Kernel A: coalesced binarize + bit-pack; also zeroes tickets.
// Block = (b, seg of 256 t).
// ---------------------------------------------------------------------------
__global__ __launch_bounds__(256) void pack_kernel(
    const float* __restrict__ x,     // [B, T, C]
    u64* __restrict__ words,         // [64][8][32]
    int* __restrict__ tickets)       // [64]
{
    const int b   = blockIdx.x >> 3;
    const int seg = blockIdx.x & 7;
    const int tid = threadIdx.x;
    const int t   = seg * 256 + tid;

    if (seg == 0 && tid == 0) tickets[b] = 0;

    const float4* xp = (const float4*)(x + ((size_t)b * T_LEN + t) * NCOMP);
    float4 v0 = xp[0];
    float4 v1 = xp[1];

    unsigned int m = 0;
    m |= (v0.x > 0.5f) ? 1u : 0u;
    m |= (v0.y > 0.5f) ? 2u : 0u;
    m |= (v0.z > 0.5f) ? 4u : 0u;
    m |= (v0.w > 0.5f) ? 8u : 0u;
    m |= (v1.x > 0.5f) ? 16u : 0u;
    m |= (v1.y > 0.5f) ? 32u : 0u;
    m |= (v1.z > 0.5f) ? 64u : 0u;
    m |= (v1.w > 0.5f) ? 128u : 0u;

    const int lane  = tid & 63;
    const int wave  = tid >> 6;
    const int chunk = seg * 4 + wave;    // 0..31

    u64 mine = 0;
    #pragma unroll
    for (int c = 0; c < NCOMP; ++c) {
        u64 wd = __ballot((m >> c) & 1u);
        if (lane == c) mine = wd;
    }
    if (lane < NCOMP) {
        words[((size_t)b * NCOMP + lane) * NCHUNK + chunk] = mine;
    }
}

// ---------------------------------------------------------------------------
// Kernel B: block per (b,c). Wave-uniform event iteration over transition
// bitmask set bits; accumulate S[h]; last block per b runs the head.
// ---------------------------------------------------------------------------
__global__ __launch_bounds__(256) void event_head_kernel(
    const u64* __restrict__ words,   // [64][8][32]
    const float* __restrict__ W1,    // [11, 64]
    const float* __restrict__ b1,
    const float* __restrict__ W2,    // [64, 64]
    const float* __restrict__ b2,
    const float* __restrict__ P1,    // [65, 64]
    const float* __restrict__ pb1,
    const float* __restrict__ P2,    // [64, 64]
    const float* __restrict__ pb2,
    float* __restrict__ partial,     // [64][8][66]
    int* __restrict__ tickets,       // [64]
    float* __restrict__ out)         // [64, 64]
{
    const int bc   = blockIdx.x;     // 0..511
    const int b    = bc >> 3;
    const int c    = bc & 7;
    const int tid  = threadIdx.x;
    const int lane = tid & 63;
    const int wave = tid >> 6;

    __shared__ u64 wsh[NCHUNK];
    __shared__ u64 tsh[NCHUNK];
    __shared__ int nxtf[NCHUNK + 1];   // first transition pos in chunks >= k
    __shared__ float Sp[4][HID];
    __shared__ int cnt_sh;
    __shared__ int last_sh;
    __shared__ float sb[HID];
    __shared__ float z[HID + 1];
    __shared__ float y[HID];

    if (tid == 0) cnt_sh = 0;
    if (tid < NCHUNK) wsh[tid] = words[((size_t)b * NCOMP + c) * NCHUNK + tid];
    __syncthreads();

    if (tid < NCHUNK) {
        u64 w = wsh[tid];
        u64 carry = (tid > 0) ? (wsh[tid - 1] >> 63) : 0ULL;
        u64 tr = w ^ ((w << 1) | carry);
        if (tid == 0) tr |= 1ULL;          // t=0 always a start
        tsh[tid] = tr;
        atomicAdd(&cnt_sh, __popcll(tr));
        int first = tr ? tid * 64 + (__ffsll((long long)tr) - 1) : T_LEN;
        // suffix-min across lanes 0..31 of wave 0
        #pragma unroll
        for (int off = 1; off < NCHUNK; off <<= 1) {
            int v = __shfl_down(first, off);
            if (tid + off < NCHUNK) first = (v < first) ? v : first;
        }
        nxtf[tid] = first;
        if (tid == 0) nxtf[NCHUNK] = T_LEN;
    }
    __syncthreads();

    // --- per-wave: 8 chunks, wave-uniform bit iteration; lanes = hid dims ---
    const float r9p   = W1[9 * HID + lane] * (1.0f / 2047.0f);
    const float r10p  = W1[10 * HID + lane] * (1.0f / 2048.0f);
    const float r9m   = r9p - r10p;                    // coefficient of t
    const float base0 = W1[c * HID + lane] + b1[lane];
    const float base1 = base0 + W1[8 * HID + lane];

    float S = 0.0f;
    for (int k = wave * 8; k < wave * 8 + 8; ++k) {
        u64 m  = tsh[k];
        u64 wb = wsh[k];
        int kb = k * 64;
        while (m) {
            int pos = __ffsll((long long)m) - 1;
            int t   = kb + pos;
            int s   = (int)((wb >> pos) & 1ULL);
            m &= m - 1;
            int nxt = m ? kb + (__ffsll((long long)m) - 1) : nxtf[k + 1];
            // a = base_s + t*(r9p - r10p) + nxt*r10p
            float a = s ? base1 : base0;
            a = fmaf((float)nxt, r10p, a);
            a = fmaf((float)t,   r9m,  a);
            S += fmaxf(a, 0.0f);
        }
    }
    Sp[wave][lane] = S;
    __syncthreads();

    float* pp = partial + (size_t)bc * PART_STRIDE;
    if (tid < HID) pp[tid] = Sp[0][tid] + Sp[1][tid] + Sp[2][tid] + Sp[3][tid];
    if (tid == HID) pp[HID] = (float)cnt_sh;

    // --- ticket: last block of this batch item runs the head ---
    __threadfence();
    __syncthreads();
    if (tid == 0) {
        int old = atomicAdd(&tickets[b], 1);
        last_sh = (old == NCOMP - 1) ? 1 : 0;
    }
    __syncthreads();
    if (!last_sh) return;
    __threadfence();

    // --- head: pooled = (S@W2)/valid + b2; z=[pooled, valid/16384]; MLP ---
    const int h = tid;
    if (h < HID) {
        float s = 0.0f, cnt = 0.0f;
        const float* pb = partial + (size_t)(b * NCOMP) * PART_STRIDE;
        #pragma unroll
        for (int cc = 0; cc < NCOMP; ++cc) {
            s   += pb[cc * PART_STRIDE + h];
            cnt += pb[cc * PART_STRIDE + HID];
        }
        float valid = fmaxf(cnt, 1.0f);
        sb[h] = s;
        z[HID] = valid / (float)MAX_EVENTS;   // all lanes same value, benign
        y[h] = valid;                          // stash valid for later
    }
    __syncthreads();
    if (h < HID) {
        float acc = 0.0f;
        #pragma unroll
        for (int k = 0; k < HID; ++k) acc = fmaf(sb[k], W2[k * HID + h], acc);
        z[h] = acc / y[0] + b2[h];            // y[0] holds valid
    }
    __syncthreads();
    if (h < HID) {
        float a1 = pb1[h];
        #pragma unroll
        for (int k = 0; k < HID + 1; ++k) a1 = fmaf(z[k], P1[k * HID + h], a1);
        y[h] = fmaxf(a1, 0.0f);
    }
    __syncthreads();
    if (h < HID) {
        float o = pb2[h];
        #pragma unroll
        for (int k = 0; k < HID; ++k) o = fmaf(y[k], P2[k * HID + h], o);
        out[(size_t)b * OUT_DIM + h] = o;
    }
}

extern "C" void kernel_launch(void* const* d_in, const int* in_sizes, int n_in,
                              void* d_out, int out_size, void* d_ws, size_t ws_size,
                              hipStream_t stream) {
    const float* x   = (const float*)d_in[0];
    const float* W1  = (const float*)d_in[1];
    const float* b1  = (const float*)d_in[2];
    const float* W2  = (const float*)d_in[3];
    const float* b2  = (const float*)d_in[4];
    const float* P1  = (const float*)d_in[5];
    const float* pb1 = (const float*)d_in[6];
    const float* P2  = (const float*)d_in[7];
    const float* pb2 = (const float*)d_in[8];
    float* out = (float*)d_out;

    u64* words     = (u64*)d_ws;
    float* partial = (float*)((char*)d_ws + WORDS_BYTES);
    int* tickets   = (int*)((char*)d_ws + WORDS_BYTES + PARTIAL_BYTES);

    pack_kernel<<<BATCH * 8, 256, 0, stream>>>(x, words, tickets);
    event_head_kernel<<<BATCH * NCOMP, 256, 0, stream>>>(
        words, W1, b1, W2, b2, P1, pb1, P2, pb2, partial, tickets, out);
}

// Round 4
// 57.334 us; speedup vs baseline: 1.3548x; 1.3548x over previous
//
#include <hip/hip_runtime.h>
#include <hip/hip_bf16.h>

#define T_LEN 2048
#define NCOMP 8
#define HID 64
#define OUT_DIM 64
#define BATCH 64
#define MAX_EVENTS (T_LEN * NCOMP)
#define NCHUNK 32              // 2048 / 64-bit chunks
#define PART_STRIDE 66         // 64 sums + count + pad

typedef unsigned long long u64;

// ws layout:
//   [0, 64*8*66*4)  : float partial[64][8][66]
//   [then, +256)    : int tickets[64]
#define PARTIAL_BYTES (64ULL * NCOMP * PART_STRIDE * 4)

// ---------------------------------------------------------------------------
// One fused kernel. Block = (b, c) with blockIdx = c*64 + b so that all 8
// channel-blocks of batch b share blockIdx%8 == b%8 (same XCD -> L2 reuse of
// the 8x re-read of x[b]).
// Phases: coalesced load+ballot -> transition masks -> parallel per-byte
// decode into compact event list -> 4-wave accumulate (hid over lanes) ->
// partial write -> ticket -> last block per b runs the head MLP.
// ---------------------------------------------------------------------------
__global__ __launch_bounds__(256) void fused_kernel(
    const float* __restrict__ x,     // [B, T, C]
    const float* __restrict__ W1,    // [11, 64]
    const float* __restrict__ b1,
    const float* __restrict__ W2,    // [64, 64]
    const float* __restrict__ b2,
    const float* __restrict__ P1,    // [65, 64]
    const float* __restrict__ pb1,
    const float* __restrict__ P2,    // [64, 64]
    const float* __restrict__ pb2,
    float* __restrict__ partial,     // [64][8][66]
    int* __restrict__ tickets,       // [64], zeroed by memset node
    float* __restrict__ out)         // [64, 64]
{
    const int b    = blockIdx.x & 63;
    const int c    = blockIdx.x >> 6;
    const int tid  = threadIdx.x;
    const int lane = tid & 63;
    const int wave = tid >> 6;

    __shared__ u64 wsh[NCHUNK];          // raw bits of channel c
    __shared__ u64 tsh[NCHUNK];          // transition (run-start) masks
    __shared__ int nxtf[NCHUNK + 1];     // first transition in chunks >= k
    __shared__ int wtot[4];
    __shared__ unsigned elist[T_LEN];    // compact events (max 2048)
    __shared__ float Sp[4][HID];
    __shared__ int last_sh;
    __shared__ float sb[HID];
    __shared__ float z[HID + 1];
    __shared__ float y[HID];

    // --- Phase 1: fully-coalesced load of x[b] rows, ballot channel c ---
    const float4* xp = (const float4*)(x + ((size_t)b * T_LEN) * NCOMP);
    #pragma unroll
    for (int i = 0; i < 8; ++i) {
        int t = i * 256 + tid;                   // lane-consecutive t
        float4 v0 = xp[t * 2];
        float4 v1 = xp[t * 2 + 1];
        unsigned m = 0;
        m |= (v0.x > 0.5f) ? 1u   : 0u;
        m |= (v0.y > 0.5f) ? 2u   : 0u;
        m |= (v0.z > 0.5f) ? 4u   : 0u;
        m |= (v0.w > 0.5f) ? 8u   : 0u;
        m |= (v1.x > 0.5f) ? 16u  : 0u;
        m |= (v1.y > 0.5f) ? 32u  : 0u;
        m |= (v1.z > 0.5f) ? 64u  : 0u;
        m |= (v1.w > 0.5f) ? 128u : 0u;
        u64 wd = __ballot((m >> c) & 1u);
        if (lane == 0) wsh[i * 4 + wave] = wd;   // chunk = i*4 + wave
    }
    __syncthreads();

    // --- Phase 2: transition masks + per-chunk suffix-min of first-start ---
    if (tid < NCHUNK) {
        u64 w = wsh[tid];
        u64 carry = (tid > 0) ? (wsh[tid - 1] >> 63) : 0ULL;
        u64 tr = w ^ ((w << 1) | carry);
        if (tid == 0) tr |= 1ULL;                // t=0 always a start
        tsh[tid] = tr;
        int first = tr ? tid * 64 + (__ffsll((long long)tr) - 1) : T_LEN;
        #pragma unroll
        for (int off = 1; off < NCHUNK; off <<= 1) {
            int v = __shfl_down(first, off);
            if (tid + off < NCHUNK) first = (v < first) ? v : first;
        }
        nxtf[tid] = first;
        if (tid == 0) nxtf[NCHUNK] = T_LEN;
    }
    __syncthreads();

    // --- Phase 3: per-byte parallel decode -> compact event list ---
    const int ch = tid >> 3;                 // chunk holding this byte
    const int sh = (tid & 7) * 8;            // bit offset of byte in chunk
    const u64 full = tsh[ch];
    const u64 wbits = wsh[ch];
    unsigned tr8 = (unsigned)((full >> sh) & 0xFFu);
    int nt = __popc(tr8);

    int incl = nt;
    #pragma unroll
    for (int o = 1; o < 64; o <<= 1) {
        int v = __shfl_up(incl, o);
        if (lane >= o) incl += v;
    }
    if (lane == 63) wtot[wave] = incl;
    __syncthreads();
    int waveoff = 0;
    for (int w = 0; w < wave; ++w) waveoff += wtot[w];
    const int nE = wtot[0] + wtot[1] + wtot[2] + wtot[3];
    int off = waveoff + incl - nt;

    unsigned rem = tr8;
    while (rem) {
        int p = __ffs(rem) - 1;
        rem &= rem - 1;
        int t = (tid << 3) + p;
        unsigned s = (unsigned)((wbits >> (sh + p)) & 1ULL);
        int nxt;
        if (rem) {
            nxt = (tid << 3) + __ffs(rem) - 1;
        } else {
            int bp = sh + 8;
            u64 above = (bp >= 64) ? 0ULL : (full & (~0ULL << bp));
            nxt = above ? ch * 64 + (__ffsll((long long)above) - 1) : nxtf[ch + 1];
        }
        elist[off++] = (unsigned)t | ((unsigned)nxt << 11) | (s << 23);
    }
    __syncthreads();

    // --- Phase 4: accumulate relu activations; hid over lanes, events split
    //     into contiguous quarters per wave, unroll x4 w/ independent accums ---
    const float r9p   = W1[9 * HID + lane] * (1.0f / 2047.0f);
    const float r10p  = W1[10 * HID + lane] * (1.0f / 2048.0f);
    const float r9m   = r9p - r10p;                  // coeff of t
    const float base0 = W1[c * HID + lane] + b1[lane];
    const float base1 = base0 + W1[8 * HID + lane];

    const int q  = (nE + 3) >> 2;
    const int i0 = wave * q;
    const int i1 = (i0 + q < nE) ? (i0 + q) : nE;

    float S0 = 0.0f, S1 = 0.0f, S2 = 0.0f, S3 = 0.0f;
    int i = i0;
    for (; i + 3 < i1; i += 4) {
        unsigned e0 = elist[i], e1 = elist[i + 1], e2 = elist[i + 2], e3 = elist[i + 3];
        float a0 = (e0 >> 23) ? base1 : base0;
        float a1 = (e1 >> 23) ? base1 : base0;
        float a2 = (e2 >> 23) ? base1 : base0;
        float a3 = (e3 >> 23) ? base1 : base0;
        a0 = fmaf((float)((e0 >> 11) & 4095u), r10p, a0);
        a1 = fmaf((float)((e1 >> 11) & 4095u), r10p, a1);
        a2 = fmaf((float)((e2 >> 11) & 4095u), r10p, a2);
        a3 = fmaf((float)((e3 >> 11) & 4095u), r10p, a3);
        a0 = fmaf((float)(e0 & 2047u), r9m, a0);
        a1 = fmaf((float)(e1 & 2047u), r9m, a1);
        a2 = fmaf((float)(e2 & 2047u), r9m, a2);
        a3 = fmaf((float)(e3 & 2047u), r9m, a3);
        S0 += fmaxf(a0, 0.0f);
        S1 += fmaxf(a1, 0.0f);
        S2 += fmaxf(a2, 0.0f);
        S3 += fmaxf(a3, 0.0f);
    }
    for (; i < i1; ++i) {
        unsigned e = elist[i];
        float a = (e >> 23) ? base1 : base0;
        a = fmaf((float)((e >> 11) & 4095u), r10p, a);
        a = fmaf((float)(e & 2047u), r9m, a);
        S0 += fmaxf(a, 0.0f);
    }
    Sp[wave][lane] = (S0 + S1) + (S2 + S3);
    __syncthreads();

    // --- Phase 5: partial write + ticket; last block of b runs the head ---
    float* pp = partial + ((size_t)b * NCOMP + c) * PART_STRIDE;
    if (tid < HID) pp[tid] = Sp[0][tid] + Sp[1][tid] + Sp[2][tid] + Sp[3][tid];
    if (tid == HID) pp[HID] = (float)nE;

    __threadfence();
    __syncthreads();
    if (tid == 0) {
        int old = atomicAdd(&tickets[b], 1);
        last_sh = (old == NCOMP - 1) ? 1 : 0;
    }
    __syncthreads();
    if (!last_sh) return;
    __threadfence();

    const int h = tid;
    if (h < HID) {
        float s = 0.0f, cnt = 0.0f;
        const float* pb = partial + (size_t)(b * NCOMP) * PART_STRIDE;
        #pragma unroll
        for (int cc = 0; cc < NCOMP; ++cc) {
            s   += pb[cc * PART_STRIDE + h];
            cnt += pb[cc * PART_STRIDE + HID];
        }
        float valid = fmaxf(cnt, 1.0f);
        sb[h] = s;
        z[HID] = valid / (float)MAX_EVENTS;
        y[h] = valid;                        // stash valid
    }
    __syncthreads();
    if (h < HID) {
        float acc = 0.0f;
        #pragma unroll
        for (int k = 0; k < HID; ++k) acc = fmaf(sb[k], W2[k * HID + h], acc);
        z[h] = acc / y[0] + b2[h];
    }
    __syncthreads();
    if (h < HID) {
        float a1 = pb1[h];
        #pragma unroll
        for (int k = 0; k < HID + 1; ++k) a1 = fmaf(z[k], P1[k * HID + h], a1);
        y[h] = fmaxf(a1, 0.0f);
    }
    __syncthreads();
    if (h < HID) {
        float o = pb2[h];
        #pragma unroll
        for (int k = 0; k < HID; ++k) o = fmaf(y[k], P2[k * HID + h], o);
        out[(size_t)b * OUT_DIM + h] = o;
    }
}

extern "C" void kernel_launch(void* const* d_in, const int* in_sizes, int n_in,
                              void* d_out, int out_size, void* d_ws, size_t ws_size,
                              hipStream_t stream) {
    const float* x   = (const float*)d_in[0];
    const float* W1  = (const float*)d_in[1];
    const float* b1  = (const float*)d_in[2];
    const float* W2  = (const float*)d_in[3];
    const float* b2  = (const float*)d_in[4];
    const float* P1  = (const float*)d_in[5];
    const float* pb1 = (const float*)d_in[6];
    const float* P2  = (const float*)d_in[7];
    const float* pb2 = (const float*)d_in[8];
    float* out = (float*)d_out;

    float* partial = (float*)d_ws;
    int* tickets   = (int*)((char*)d_ws + PARTIAL_BYTES);

    hipMemsetAsync(tickets, 0, BATCH * sizeof(int), stream);
    fused_kernel<<<BATCH * NCOMP, 256, 0, stream>>>(
        x, W1, b1, W2, b2, P1, pb1, P2, pb2, partial, tickets, out);
}

// Round 5
// 21.317 us; speedup vs baseline: 3.6438x; 2.6896x over previous
//
#include <hip/hip_runtime.h>
#include <hip/hip_bf16.h>

#define T_LEN 2048
#define NCOMP 8
#define HID 64
#define OUT_DIM 64
#define BATCH 64
#define MAX_EVENTS (T_LEN * NCOMP)
#define NCHUNK 32              // 2048 / 64-bit chunks
#define PART_STRIDE 66         // 64 sums + count + pad
#define NWAVE 8                // 512-thread blocks

typedef unsigned long long u64;

// ws layout: [0, 64*8*66*4) : float partial[64][8][66]
#define PARTIAL_BYTES (64ULL * NCOMP * PART_STRIDE * 4)

// ---------------------------------------------------------------------------
// Kernel 1: block per (b,c), 512 threads. Coalesced load of x[b] + ballot of
// channel c -> transition masks -> parallel per-nibble decode into compact
// event list -> 8-wave accumulate (hid dims over lanes). Plain stores of the
// 64-dim partial + count. NO device-scope fences or atomics (R3/R4 lesson:
// 512 block-level threadfence+ticket cost ~40us on gfx950 due to per-XCD L2
// writeback/invalidate + serialized far atomics).
// blockIdx = c*64 + b so the 8 readers of x[b] share blockIdx%8 -> same XCD L2.
// ---------------------------------------------------------------------------
__global__ __launch_bounds__(512) void event_kernel(
    const float* __restrict__ x,     // [B, T, C]
    const float* __restrict__ W1,    // [11, 64]
    const float* __restrict__ b1,    // [64]
    float* __restrict__ partial)     // [64][8][66]
{
    const int b    = blockIdx.x & 63;
    const int c    = blockIdx.x >> 6;
    const int tid  = threadIdx.x;
    const int lane = tid & 63;
    const int wave = tid >> 6;

    __shared__ u64 wsh[NCHUNK];          // raw bits of channel c
    __shared__ u64 tsh[NCHUNK];          // transition (run-start) masks
    __shared__ int nxtf[NCHUNK + 1];     // first transition in chunks >= k
    __shared__ int wtot[NWAVE];
    __shared__ unsigned elist[T_LEN];    // compact events
    __shared__ float Sp[NWAVE][HID];

    // --- Phase 1: coalesced load + ballot channel c ---
    const float4* xp = (const float4*)(x + ((size_t)b * T_LEN) * NCOMP);
    #pragma unroll
    for (int i = 0; i < 4; ++i) {
        int t = i * 512 + tid;
        float4 v0 = xp[t * 2];
        float4 v1 = xp[t * 2 + 1];
        unsigned m = 0;
        m |= (v0.x > 0.5f) ? 1u   : 0u;
        m |= (v0.y > 0.5f) ? 2u   : 0u;
        m |= (v0.z > 0.5f) ? 4u   : 0u;
        m |= (v0.w > 0.5f) ? 8u   : 0u;
        m |= (v1.x > 0.5f) ? 16u  : 0u;
        m |= (v1.y > 0.5f) ? 32u  : 0u;
        m |= (v1.z > 0.5f) ? 64u  : 0u;
        m |= (v1.w > 0.5f) ? 128u : 0u;
        u64 wd = __ballot((m >> c) & 1u);
        if (lane == 0) wsh[i * 8 + wave] = wd;   // chunk = i*8 + wave
    }
    __syncthreads();

    // --- Phase 2: transition masks + suffix-min of first-transition ---
    if (tid < NCHUNK) {
        u64 w = wsh[tid];
        u64 carry = (tid > 0) ? (wsh[tid - 1] >> 63) : 0ULL;
        u64 tr = w ^ ((w << 1) | carry);
        if (tid == 0) tr |= 1ULL;                // t=0 always a start
        tsh[tid] = tr;
        int first = tr ? tid * 64 + (__ffsll((long long)tr) - 1) : T_LEN;
        #pragma unroll
        for (int off = 1; off < NCHUNK; off <<= 1) {
            int v = __shfl_down(first, off);
            if (tid + off < NCHUNK) first = (v < first) ? v : first;
        }
        nxtf[tid] = first;
        if (tid == 0) nxtf[NCHUNK] = T_LEN;
    }
    __syncthreads();

    // --- Phase 3: per-nibble parallel decode -> compact event list ---
    const int ch = tid >> 4;                 // 16 threads per chunk
    const int sh = (tid & 15) * 4;           // bit offset of nibble
    const u64 full  = tsh[ch];
    const u64 wbits = wsh[ch];
    unsigned tr4 = (unsigned)((full >> sh) & 0xFu);
    int nt = __popc(tr4);

    int incl = nt;
    #pragma unroll
    for (int o = 1; o < 64; o <<= 1) {
        int v = __shfl_up(incl, o);
        if (lane >= o) incl += v;
    }
    if (lane == 63) wtot[wave] = incl;
    __syncthreads();
    int waveoff = 0;
    for (int w = 0; w < wave; ++w) waveoff += wtot[w];
    int nE = 0;
    #pragma unroll
    for (int w = 0; w < NWAVE; ++w) nE += wtot[w];
    int off = waveoff + incl - nt;

    unsigned rem = tr4;
    while (rem) {
        int p = __ffs(rem) - 1;
        rem &= rem - 1;
        int t = (tid << 2) + p;
        unsigned s = (unsigned)((wbits >> (sh + p)) & 1ULL);
        int nxt;
        if (rem) {
            nxt = (tid << 2) + __ffs(rem) - 1;
        } else {
            int bp = sh + 4;
            u64 above = (bp >= 64) ? 0ULL : (full & (~0ULL << bp));
            nxt = above ? ch * 64 + (__ffsll((long long)above) - 1) : nxtf[ch + 1];
        }
        elist[off++] = (unsigned)t | ((unsigned)nxt << 11) | (s << 23);
    }
    __syncthreads();

    // --- Phase 4: accumulate; events in contiguous eighths, uint4 LDS reads ---
    const float r9p   = W1[9 * HID + lane] * (1.0f / 2047.0f);
    const float r10p  = W1[10 * HID + lane] * (1.0f / 2048.0f);
    const float r9m   = r9p - r10p;                  // coeff of t
    const float base0 = W1[c * HID + lane] + b1[lane];
    const float base1 = base0 + W1[8 * HID + lane];

    const int oct = ((nE + 31) >> 5) << 2;           // per-wave span, mult of 4
    const int i0  = wave * oct;
    const int i1  = (i0 + oct < nE) ? (i0 + oct) : nE;

    float S0 = 0.0f, S1 = 0.0f, S2 = 0.0f, S3 = 0.0f;
    int i = i0;
    for (; i + 3 < i1; i += 4) {
        uint4 e = *(const uint4*)&elist[i];          // ds_read_b128, broadcast
        float a0 = (e.x >> 23) ? base1 : base0;
        float a1 = (e.y >> 23) ? base1 : base0;
        float a2 = (e.z >> 23) ? base1 : base0;
        float a3 = (e.w >> 23) ? base1 : base0;
        a0 = fmaf((float)((e.x >> 11) & 4095u), r10p, a0);
        a1 = fmaf((float)((e.y >> 11) & 4095u), r10p, a1);
        a2 = fmaf((float)((e.z >> 11) & 4095u), r10p, a2);
        a3 = fmaf((float)((e.w >> 11) & 4095u), r10p, a3);
        a0 = fmaf((float)(e.x & 2047u), r9m, a0);
        a1 = fmaf((float)(e.y & 2047u), r9m, a1);
        a2 = fmaf((float)(e.z & 2047u), r9m, a2);
        a3 = fmaf((float)(e.w & 2047u), r9m, a3);
        S0 += fmaxf(a0, 0.0f);
        S1 += fmaxf(a1, 0.0f);
        S2 += fmaxf(a2, 0.0f);
        S3 += fmaxf(a3, 0.0f);
    }
    for (; i < i1; ++i) {
        unsigned e = elist[i];
        float a = (e >> 23) ? base1 : base0;
        a = fmaf((float)((e >> 11) & 4095u), r10p, a);
        a = fmaf((float)(e & 2047u), r9m, a);
        S0 += fmaxf(a, 0.0f);
    }
    Sp[wave][lane] = (S0 + S1) + (S2 + S3);
    __syncthreads();

    // --- Phase 5: plain partial store ---
    float* pp = partial + ((size_t)b * NCOMP + c) * PART_STRIDE;
    if (tid < HID) {
        float s = 0.0f;
        #pragma unroll
        for (int w = 0; w < NWAVE; ++w) s += Sp[w][tid];
        pp[tid] = s;
    }
    if (tid == HID) pp[HID] = (float)nE;
}

// ---------------------------------------------------------------------------
// Kernel 2: head. pooled = (S @ W2)/valid + b2; z = [pooled, valid/16384];
// out = relu(z @ P1 + pb1) @ P2 + pb2.  (R2's proven version.)
// ---------------------------------------------------------------------------
__global__ __launch_bounds__(64) void head_kernel(
    const float* __restrict__ partial,  // [64][8][66]
    const float* __restrict__ W2,
    const float* __restrict__ b2,
    const float* __restrict__ P1,
    const float* __restrict__ pb1,
    const float* __restrict__ P2,
    const float* __restrict__ pb2,
    float* __restrict__ out)
{
    const int b = blockIdx.x;
    const int h = threadIdx.x;

    __shared__ float sb[HID];
    __shared__ float z[HID + 1];
    __shared__ float y[HID];

    float s = 0.0f, cnt = 0.0f;
    #pragma unroll
    for (int cc = 0; cc < NCOMP; ++cc) {
        const float* pp = partial + ((size_t)b * NCOMP + cc) * PART_STRIDE;
        s   += pp[h];
        cnt += pp[HID];
    }
    float valid = fmaxf(cnt, 1.0f);
    sb[h] = s;
    __syncthreads();

    float acc = 0.0f;
    #pragma unroll
    for (int k = 0; k < HID; ++k) acc = fmaf(sb[k], W2[k * HID + h], acc);
    z[h] = acc / valid + b2[h];
    if (h == 0) z[HID] = valid / (float)MAX_EVENTS;
    __syncthreads();

    float a1 = pb1[h];
    #pragma unroll
    for (int k = 0; k < HID + 1; ++k) a1 = fmaf(z[k], P1[k * HID + h], a1);
    y[h] = fmaxf(a1, 0.0f);
    __syncthreads();

    float o = pb2[h];
    #pragma unroll
    for (int k = 0; k < HID; ++k) o = fmaf(y[k], P2[k * HID + h], o);
    out[(size_t)b * OUT_DIM + h] = o;
}

extern "C" void kernel_launch(void* const* d_in, const int* in_sizes, int n_in,
                              void* d_out, int out_size, void* d_ws, size_t ws_size,
                              hipStream_t stream) {
    const float* x   = (const float*)d_in[0];
    const float* W1  = (const float*)d_in[1];
    const float* b1  = (const float*)d_in[2];
    const float* W2  = (const float*)d_in[3];
    const float* b2  = (const float*)d_in[4];
    const float* P1  = (const float*)d_in[5];
    const float* pb1 = (const float*)d_in[6];
    const float* P2  = (const float*)d_in[7];
    const float* pb2 = (const float*)d_in[8];
    float* out = (float*)d_out;

    float* partial = (float*)d_ws;

    event_kernel<<<BATCH * NCOMP, 512, 0, stream>>>(x, W1, b1, partial);
    head_kernel<<<BATCH, 64, 0, stream>>>(partial, W2, b2, P1, pb1, P2, pb2, out);
}

// Round 6
// 19.957 us; speedup vs baseline: 3.8921x; 1.0682x over previous
//
#include <hip/hip_runtime.h>
#include <hip/hip_bf16.h>

#define T_LEN 2048
#define NCOMP 8
#define HID 64
#define OUT_DIM 64
#define BATCH 64
#define MAX_EVENTS (T_LEN * NCOMP)
#define NCHUNK 32              // 2048 / 64-bit chunks
#define PART_STRIDE 66         // 64 sums + count + pad
#define NWAVE 8                // 512-thread blocks

typedef unsigned long long u64;

// ws layout: [0, 64*8*66*4) : float partial[64][8][66]
#define PARTIAL_BYTES (64ULL * NCOMP * PART_STRIDE * 4)

// ---------------------------------------------------------------------------
// Kernel 1: block per (b,c), 512 threads. Coalesced load of x[b] + ballot of
// channel c -> transition masks -> parallel per-nibble decode into a compact
// event list of float4 {s, t, nxt, 0} (decode cost paid ONCE per event in
// phase 3, not redundantly by all 64 lanes in phase 4) -> 8-wave accumulate
// at 5 VALU/event -> plain partial store. No device-scope fences/atomics
// (R4 lesson: 512 block fences+tickets cost ~35us).
// blockIdx = c*64 + b so the 8 readers of x[b] share blockIdx%8 -> same XCD L2.
// ---------------------------------------------------------------------------
__global__ __launch_bounds__(512) void event_kernel(
    const float* __restrict__ x,     // [B, T, C]
    const float* __restrict__ W1,    // [11, 64]
    const float* __restrict__ b1,    // [64]
    float* __restrict__ partial)     // [64][8][66]
{
    const int b    = blockIdx.x & 63;
    const int c    = blockIdx.x >> 6;
    const int tid  = threadIdx.x;
    const int lane = tid & 63;
    const int wave = tid >> 6;

    __shared__ u64 wsh[NCHUNK];          // raw bits of channel c
    __shared__ u64 tsh[NCHUNK];          // transition (run-start) masks
    __shared__ int nxtf[NCHUNK + 1];     // first transition in chunks >= k
    __shared__ int wtot[NWAVE];
    __shared__ float4 elist[T_LEN];      // compact events {s, t, nxt, 0}
    __shared__ float Sp[NWAVE][HID];

    // --- Phase 1: coalesced load + ballot channel c ---
    const float4* xp = (const float4*)(x + ((size_t)b * T_LEN) * NCOMP);
    #pragma unroll
    for (int i = 0; i < 4; ++i) {
        int t = i * 512 + tid;
        float4 v0 = xp[t * 2];
        float4 v1 = xp[t * 2 + 1];
        unsigned m = 0;
        m |= (v0.x > 0.5f) ? 1u   : 0u;
        m |= (v0.y > 0.5f) ? 2u   : 0u;
        m |= (v0.z > 0.5f) ? 4u   : 0u;
        m |= (v0.w > 0.5f) ? 8u   : 0u;
        m |= (v1.x > 0.5f) ? 16u  : 0u;
        m |= (v1.y > 0.5f) ? 32u  : 0u;
        m |= (v1.z > 0.5f) ? 64u  : 0u;
        m |= (v1.w > 0.5f) ? 128u : 0u;
        u64 wd = __ballot((m >> c) & 1u);
        if (lane == 0) wsh[i * 8 + wave] = wd;   // chunk = i*8 + wave
    }
    __syncthreads();

    // --- Phase 2: transition masks + suffix-min of first-transition ---
    if (tid < NCHUNK) {
        u64 w = wsh[tid];
        u64 carry = (tid > 0) ? (wsh[tid - 1] >> 63) : 0ULL;
        u64 tr = w ^ ((w << 1) | carry);
        if (tid == 0) tr |= 1ULL;                // t=0 always a start
        tsh[tid] = tr;
        int first = tr ? tid * 64 + (__ffsll((long long)tr) - 1) : T_LEN;
        #pragma unroll
        for (int off = 1; off < NCHUNK; off <<= 1) {
            int v = __shfl_down(first, off);
            if (tid + off < NCHUNK) first = (v < first) ? v : first;
        }
        nxtf[tid] = first;
        if (tid == 0) nxtf[NCHUNK] = T_LEN;
    }
    __syncthreads();

    // --- Phase 3: per-nibble parallel decode -> compact float4 event list ---
    const int ch = tid >> 4;                 // 16 threads per chunk
    const int sh = (tid & 15) * 4;           // bit offset of nibble
    const u64 full  = tsh[ch];
    const u64 wbits = wsh[ch];
    unsigned tr4 = (unsigned)((full >> sh) & 0xFu);
    int nt = __popc(tr4);

    int incl = nt;
    #pragma unroll
    for (int o = 1; o < 64; o <<= 1) {
        int v = __shfl_up(incl, o);
        if (lane >= o) incl += v;
    }
    if (lane == 63) wtot[wave] = incl;
    __syncthreads();
    int waveoff = 0;
    for (int w = 0; w < wave; ++w) waveoff += wtot[w];
    int nE = 0;
    #pragma unroll
    for (int w = 0; w < NWAVE; ++w) nE += wtot[w];
    int off = waveoff + incl - nt;

    unsigned rem = tr4;
    while (rem) {
        int p = __ffs(rem) - 1;
        rem &= rem - 1;
        int t = (tid << 2) + p;
        unsigned s = (unsigned)((wbits >> (sh + p)) & 1ULL);
        int nxt;
        if (rem) {
            nxt = (tid << 2) + __ffs(rem) - 1;
        } else {
            int bp = sh + 4;
            u64 above = (bp >= 64) ? 0ULL : (full & (~0ULL << bp));
            nxt = above ? ch * 64 + (__ffsll((long long)above) - 1) : nxtf[ch + 1];
        }
        elist[off].x = (float)s;
        elist[off].y = (float)t;
        elist[off].z = (float)nxt;
        elist[off].w = 0.0f;
        ++off;
    }
    __syncthreads();

    // --- Phase 4: accumulate, 5 VALU per event; contiguous eighths per wave ---
    const float r8    = W1[8 * HID + lane];
    const float r9p   = W1[9 * HID + lane] * (1.0f / 2047.0f);
    const float r10p  = W1[10 * HID + lane] * (1.0f / 2048.0f);
    const float r9m   = r9p - r10p;                  // coeff of t
    const float base0 = W1[c * HID + lane] + b1[lane];

    const int oct = ((nE + 31) >> 5) << 2;           // per-wave span, mult of 4
    const int i0  = wave * oct;
    const int i1  = (i0 + oct < nE) ? (i0 + oct) : nE;

    float S0 = 0.0f, S1 = 0.0f, S2 = 0.0f, S3 = 0.0f;
    int i = i0;
    for (; i + 3 < i1; i += 4) {
        float4 e0 = elist[i];
        float4 e1 = elist[i + 1];
        float4 e2 = elist[i + 2];
        float4 e3 = elist[i + 3];
        float a0 = fmaf(e0.x, r8, base0);            // == base_s exactly
        float a1 = fmaf(e1.x, r8, base0);
        float a2 = fmaf(e2.x, r8, base0);
        float a3 = fmaf(e3.x, r8, base0);
        a0 = fmaf(e0.z, r10p, a0);
        a1 = fmaf(e1.z, r10p, a1);
        a2 = fmaf(e2.z, r10p, a2);
        a3 = fmaf(e3.z, r10p, a3);
        a0 = fmaf(e0.y, r9m, a0);
        a1 = fmaf(e1.y, r9m, a1);
        a2 = fmaf(e2.y, r9m, a2);
        a3 = fmaf(e3.y, r9m, a3);
        S0 += fmaxf(a0, 0.0f);
        S1 += fmaxf(a1, 0.0f);
        S2 += fmaxf(a2, 0.0f);
        S3 += fmaxf(a3, 0.0f);
    }
    for (; i < i1; ++i) {
        float4 e = elist[i];
        float a = fmaf(e.x, r8, base0);
        a = fmaf(e.z, r10p, a);
        a = fmaf(e.y, r9m, a);
        S0 += fmaxf(a, 0.0f);
    }
    Sp[wave][lane] = (S0 + S1) + (S2 + S3);
    __syncthreads();

    // --- Phase 5: plain partial store ---
    float* pp = partial + ((size_t)b * NCOMP + c) * PART_STRIDE;
    if (tid < HID) {
        float s = 0.0f;
        #pragma unroll
        for (int w = 0; w < NWAVE; ++w) s += Sp[w][tid];
        pp[tid] = s;
    }
    if (tid == HID) pp[HID] = (float)nE;
}

// ---------------------------------------------------------------------------
// Kernel 2: head. pooled = (S @ W2)/valid + b2; z = [pooled, valid/16384];
// out = relu(z @ P1 + pb1) @ P2 + pb2.
// ---------------------------------------------------------------------------
__global__ __launch_bounds__(64) void head_kernel(
    const float* __restrict__ partial,  // [64][8][66]
    const float* __restrict__ W2,
    const float* __restrict__ b2,
    const float* __restrict__ P1,
    const float* __restrict__ pb1,
    const float* __restrict__ P2,
    const float* __restrict__ pb2,
    float* __restrict__ out)
{
    const int b = blockIdx.x;
    const int h = threadIdx.x;

    __shared__ float sb[HID];
    __shared__ float z[HID + 1];
    __shared__ float y[HID];

    float s = 0.0f, cnt = 0.0f;
    #pragma unroll
    for (int cc = 0; cc < NCOMP; ++cc) {
        const float* pp = partial + ((size_t)b * NCOMP + cc) * PART_STRIDE;
        s   += pp[h];
        cnt += pp[HID];
    }
    float valid = fmaxf(cnt, 1.0f);
    sb[h] = s;
    __syncthreads();

    float acc = 0.0f;
    #pragma unroll
    for (int k = 0; k < HID; ++k) acc = fmaf(sb[k], W2[k * HID + h], acc);
    z[h] = acc / valid + b2[h];
    if (h == 0) z[HID] = valid / (float)MAX_EVENTS;
    __syncthreads();

    float a1 = pb1[h];
    #pragma unroll
    for (int k = 0; k < HID + 1; ++k) a1 = fmaf(z[k], P1[k * HID + h], a1);
    y[h] = fmaxf(a1, 0.0f);
    __syncthreads();

    float o = pb2[h];
    #pragma unroll
    for (int k = 0; k < HID; ++k) o = fmaf(y[k], P2[k * HID + h], o);
    out[(size_t)b * OUT_DIM + h] = o;
}

extern "C" void kernel_launch(void* const* d_in, const int* in_sizes, int n_in,
                              void* d_out, int out_size, void* d_ws, size_t ws_size,
                              hipStream_t stream) {
    const float* x   = (const float*)d_in[0];
    const float* W1  = (const float*)d_in[1];
    const float* b1  = (const float*)d_in[2];
    const float* W2  = (const float*)d_in[3];
    const float* b2  = (const float*)d_in[4];
    const float* P1  = (const float*)d_in[5];
    const float* pb1 = (const float*)d_in[6];
    const float* P2  = (const float*)d_in[7];
    const float* pb2 = (const float*)d_in[8];
    float* out = (float*)d_out;

    float* partial = (float*)d_ws;

    event_kernel<<<BATCH * NCOMP, 512, 0, stream>>>(x, W1, b1, partial);
    head_kernel<<<BATCH, 64, 0, stream>>>(partial, W2, b2, P1, pb1, P2, pb2, out);
}